// Round 6
// baseline (343.037 us; speedup 1.0000x reference)
//
#include <hip/hip_runtime.h>
#include <hip/hip_bf16.h>
#include <float.h>
#include <math.h>

typedef __bf16 bfx;
typedef __attribute__((ext_vector_type(8))) __bf16 bf16x8;
typedef __attribute__((ext_vector_type(4))) __bf16 bf16x4;
typedef __attribute__((ext_vector_type(2))) __bf16 bf16x2;
typedef __attribute__((ext_vector_type(4))) float f32x4;

#define SEQ    512
#define CDIM   256
#define NH     8
#define DH     64
#define INNERD 512
#define RT     32
#define NB     2
#define KW     15
#define PW     7
#define LDT    40   // padded LDS row stride (bf16): 80B rows -> <=2-way conflicts
#define TST    140  // epilogue stage stride (bf16): 70 dwords -> quads on disjoint banks

// ================= fused prep: cvt x, sincos, cvt pw, tcvt wkv/wo, mask ====
__global__ void prep_kernel(const float* __restrict__ x,
                            const float* __restrict__ pw_w,
                            const float* __restrict__ w_kv,
                            const float* __restrict__ w_o,
                            const int*   __restrict__ mask,
                            bfx* __restrict__ xb16, bfx* __restrict__ pw16,
                            bfx* __restrict__ wkvT, bfx* __restrict__ woT,
                            float* __restrict__ tab,
                            int* __restrict__ m_any, int* __restrict__ has_rows,
                            float* __restrict__ inv_nr) {
    int bid = blockIdx.x, tid = threadIdx.x;
    if (bid < 8192) {                       // x -> bf16, 4 elems/thread
        int idx = bid * 256 + tid;
        float4 v = ((const float4*)x)[idx];
        bfx* d = xb16 + idx * 4;
        d[0] = (bfx)v.x; d[1] = (bfx)v.y; d[2] = (bfx)v.z; d[3] = (bfx)v.w;
        return;
    }
    int b2 = bid - 8192;
    if (b2 < 64) {                          // sincos table
        int idx = b2 * 256 + tid;
        int i = idx >> 5, j = idx & 31;
        float inv_freq = powf(10000.0f, -(float)j / 32.0f);
        float s, c;
        sincosf((float)i * inv_freq, &s, &c);
        tab[idx * 2] = s; tab[idx * 2 + 1] = c;
        return;
    }
    b2 -= 64;
    if (b2 < 128) {                         // pw_w -> bf16 (already [n][k])
        int idx = b2 * 256 + tid;
        float4 v = ((const float4*)pw_w)[idx];
        bfx* d = pw16 + idx * 4;
        d[0] = (bfx)v.x; d[1] = (bfx)v.y; d[2] = (bfx)v.z; d[3] = (bfx)v.w;
        return;
    }
    b2 -= 128;
    if (b2 < 1024) {                        // w_kv transpose: wkvT[n*256+k]
        int idx = b2 * 256 + tid;
        int k = idx & 255, n = idx >> 8;
        wkvT[idx] = (bfx)w_kv[(size_t)k * 1024 + n];
        return;
    }
    b2 -= 1024;
    if (b2 < 512) {                         // w_o transpose: woT[n*512+k]
        int idx = b2 * 256 + tid;
        int k = idx & 511, n = idx >> 9;
        woT[idx] = (bfx)w_o[(size_t)k * CDIM + n];
        return;
    }
    b2 -= 512;
    {                                       // mask stats, b = b2 (0..1)
        int b = b2;
        #pragma unroll
        for (int half = 0; half < 2; ++half) {
            int i = tid + half * 256;
            int any_col = 0;
            for (int rr = 0; rr < RT; ++rr)
                any_col |= mask[(size_t)(b * RT + rr) * SEQ + i];
            m_any[b * SEQ + i] = any_col ? 1 : 0;
        }
        __shared__ int hr[RT];
        if (tid < RT) {
            int a = 0;
            const int* mrow = mask + (size_t)(b * RT + tid) * SEQ;
            for (int j = 0; j < SEQ; ++j) a |= mrow[j];
            hr[tid] = a ? 1 : 0;
            has_rows[b * RT + tid] = hr[tid];
        }
        __syncthreads();
        if (tid == 0) {
            int s = 0;
            for (int rr = 0; rr < RT; ++rr) s += hr[rr];
            inv_nr[b] = (s > 0) ? rsqrtf((float)s) : 0.0f;
        }
    }
}

// ---------------- depthwise conv1d: 2 ch/thread, 32-row chunks -------------
__global__ void conv_kernel(const bfx* __restrict__ xb,
                            const float* __restrict__ dw_w,
                            const float* __restrict__ dw_b,
                            bfx* __restrict__ hdw) {
    int bn  = blockIdx.x;
    int grp = threadIdx.x >> 7;
    int t   = threadIdx.x & 127;
    int i0  = blockIdx.y * 64 + grp * 32;
    int c   = t * 2;
    const bf16x2* xc = (const bf16x2*)(xb + (size_t)bn * SEQ * CDIM) + t;
    float w0[KW], w1[KW];
    #pragma unroll
    for (int k = 0; k < KW; ++k) { w0[k] = dw_w[c * KW + k]; w1[k] = dw_w[(c + 1) * KW + k]; }
    float b0 = dw_b[c], b1 = dw_b[c + 1];
    float win0[KW], win1[KW];
    #pragma unroll
    for (int k = 0; k < KW; ++k) {
        int p = i0 - PW + k;
        if (p >= 0 && p < SEQ) {
            bf16x2 v = xc[(size_t)p * 128];
            win0[k] = (float)v[0]; win1[k] = (float)v[1];
        } else { win0[k] = 0.0f; win1[k] = 0.0f; }
    }
    bf16x2* orow = (bf16x2*)(hdw + ((size_t)bn * SEQ + i0) * CDIM) + t;
    for (int i = i0; i < i0 + 32; ++i) {
        float a0 = b0, a1 = b1;
        #pragma unroll
        for (int k = 0; k < KW; ++k) { a0 += win0[k] * w0[k]; a1 += win1[k] * w1[k]; }
        bf16x2 o; o[0] = (bfx)a0; o[1] = (bfx)a1;
        *orow = o;
        orow += 128;
        #pragma unroll
        for (int k = 0; k < KW - 1; ++k) { win0[k] = win0[k + 1]; win1[k] = win1[k + 1]; }
        int p = i + PW + 1;
        if (p < SEQ) {
            bf16x2 v = xc[(size_t)p * 128];
            win0[KW - 1] = (float)v[0]; win1[KW - 1] = (float)v[1];
        } else { win0[KW - 1] = 0.0f; win1[KW - 1] = 0.0f; }
    }
}

// ---------------- shared 128x128 MFMA tile ---------------------------------
__device__ __forceinline__ void gemm_tile(const bfx* __restrict__ A, int lda,
                                          const bfx* __restrict__ B, int ldb,
                                          int m0, int n0, int K,
                                          bfx* As, bfx* Bs, f32x4 acc[4][4]) {
    int tid = threadIdx.x;
    int wave = tid >> 6, lane = tid & 63;
    int wm = (wave >> 1) * 64, wn = (wave & 1) * 64;
    int col = lane & 15, quad = lane >> 4;
    for (int k0 = 0; k0 < K; k0 += 32) {
        #pragma unroll
        for (int r = 0; r < 2; ++r) {
            int v = tid + r * 256;
            int row = v >> 2, kv = (v & 3) * 8;
            *(bf16x8*)&As[row * LDT + kv] = *(const bf16x8*)&A[(size_t)(m0 + row) * lda + k0 + kv];
            *(bf16x8*)&Bs[row * LDT + kv] = *(const bf16x8*)&B[(size_t)(n0 + row) * ldb + k0 + kv];
        }
        __syncthreads();
        bf16x8 af[4], bff[4];
        #pragma unroll
        for (int f = 0; f < 4; ++f) {
            af[f]  = *(const bf16x8*)&As[(wm + f * 16 + col) * LDT + quad * 8];
            bff[f] = *(const bf16x8*)&Bs[(wn + f * 16 + col) * LDT + quad * 8];
        }
        #pragma unroll
        for (int mi = 0; mi < 4; ++mi)
            #pragma unroll
            for (int ni = 0; ni < 4; ++ni)
                acc[mi][ni] = __builtin_amdgcn_mfma_f32_16x16x32_bf16(af[mi], bff[ni], acc[mi][ni], 0, 0, 0);
        __syncthreads();
    }
}

#define GEMM_PROLOGUE \
    __shared__ __align__(16) bfx smem[2 * 128 * LDT]; \
    bfx* As = smem; bfx* Bs = smem + 128 * LDT; \
    f32x4 acc[4][4]; \
    _Pragma("unroll") for (int i_ = 0; i_ < 4; ++i_) \
    _Pragma("unroll") for (int j_ = 0; j_ < 4; ++j_) acc[i_][j_] = (f32x4){0.f, 0.f, 0.f, 0.f}; \
    int tid = threadIdx.x; \
    int wave = tid >> 6, lane = tid & 63; \
    int wm = (wave >> 1) * 64, wn = (wave & 1) * 64; \
    int col = lane & 15, quad = lane >> 4;

// ---------------- q GEMM: hdw[32768,256] @ pw16^T -> rotary -> Qr ----------
// epilogue: LDS re-tile -> 16B coalesced stores (no 2B write-allocate RMW)
__global__ void qgemm_kernel(const bfx* __restrict__ A, const bfx* __restrict__ B,
                             const float* __restrict__ pw_b,
                             const int* __restrict__ has_rows,
                             const float* __restrict__ inv_nr,
                             const float* __restrict__ tab,
                             bfx* __restrict__ Qr) {
    GEMM_PROLOGUE
    int m0 = blockIdx.y * 128, n0 = blockIdx.x * 128;
    gemm_tile(A, CDIM, B, CDIM, m0, n0, CDIM, As, Bs, acc);
    int bn = m0 >> 9, b = bn >> 5, rr = bn & 31;
    int i0 = m0 & (SEQ - 1);
    float zs = has_rows[bn] ? 0.125f * inv_nr[b] : 0.0f;
    bfx* Ts = smem;
    #pragma unroll
    for (int p = 0; p < 2; ++p) {
        __syncthreads();
        if ((wave >> 1) == p) {
            #pragma unroll
            for (int mi = 0; mi < 4; ++mi)
                #pragma unroll
                for (int ni = 0; ni < 4; ++ni)
                    #pragma unroll
                    for (int rg = 0; rg < 4; ++rg) {
                        int rl = mi * 16 + quad * 4 + rg;
                        int i  = i0 + p * 64 + rl;
                        int o  = n0 + wn + ni * 16 + col;
                        float v  = acc[mi][ni][rg];
                        float vp = __shfl_xor(v, 1);
                        float q  = v + pw_b[o];
                        float qp = vp + pw_b[o ^ 1];
                        int j = (o & 63) >> 1;
                        float sn = tab[(i * 32 + j) * 2], cs = tab[(i * 32 + j) * 2 + 1];
                        float r = (o & 1) ? (q * cs + qp * sn) : (q * cs - qp * sn);
                        Ts[rl * TST + wn + ni * 16 + col] = (bfx)(r * zs);
                    }
        }
        __syncthreads();
        #pragma unroll
        for (int e = 0; e < 4; ++e) {
            int rl = (tid >> 4) + e * 16;
            int chunk = tid & 15;
            bf16x8 v = *(const bf16x8*)&Ts[rl * TST + chunk * 8];
            int i = i0 + p * 64 + rl;
            int o = n0 + chunk * 8;
            int h = o >> 6, dd = o & 63;
            *(bf16x8*)&Qr[((size_t)((b * NH + h) * SEQ + i)) * 2048 + rr * 64 + dd] = v;
        }
    }
}

// ---------------- kv GEMM: xb[32768,256] @ wkvT^T ---------------------------
// blockIdx.x<4: K half -> rotary -> LDS re-tile -> coalesced Kr stores
// blockIdx.x>=4: V half -> LDS transpose -> coalesced Vt[bh][rd][i] stores
__global__ void kvgemm_kernel(const bfx* __restrict__ A, const bfx* __restrict__ B,
                              const float* __restrict__ tab,
                              bfx* __restrict__ Kr, bfx* __restrict__ Vt) {
    GEMM_PROLOGUE
    int m0 = blockIdx.y * 128, n0 = blockIdx.x * 128;
    gemm_tile(A, CDIM, B, CDIM, m0, n0, CDIM, As, Bs, acc);
    int bn = m0 >> 9, b = bn >> 5, rr = bn & 31;
    int i0 = m0 & (SEQ - 1);
    bfx* Ts = smem;                 // 64 x TST bf16 = 17920 B <= 20480 B
    if (blockIdx.x < 4) {
        // ---- K half: rotary -> LDS -> 16B stores ----
        #pragma unroll
        for (int p = 0; p < 2; ++p) {
            __syncthreads();
            if ((wave >> 1) == p) {
                #pragma unroll
                for (int mi = 0; mi < 4; ++mi)
                    #pragma unroll
                    for (int ni = 0; ni < 4; ++ni)
                        #pragma unroll
                        for (int rg = 0; rg < 4; ++rg) {
                            int rl = mi * 16 + quad * 4 + rg;
                            int i  = i0 + p * 64 + rl;
                            int o  = n0 + wn + ni * 16 + col;
                            float v  = acc[mi][ni][rg];
                            float vp = __shfl_xor(v, 1);
                            int j = (o & 63) >> 1;
                            float sn = tab[(i * 32 + j) * 2], cs = tab[(i * 32 + j) * 2 + 1];
                            float r = (o & 1) ? (v * cs + vp * sn) : (v * cs - vp * sn);
                            Ts[rl * TST + wn + ni * 16 + col] = (bfx)r;
                        }
            }
            __syncthreads();
            #pragma unroll
            for (int e = 0; e < 4; ++e) {
                int rl = (tid >> 4) + e * 16;
                int chunk = tid & 15;
                bf16x8 v = *(const bf16x8*)&Ts[rl * TST + chunk * 8];
                int i = i0 + p * 64 + rl;
                int o = n0 + chunk * 8;
                int h = o >> 6, dd = o & 63;
                *(bf16x8*)&Kr[((size_t)((b * NH + h) * SEQ + i)) * 2048 + rr * 64 + dd] = v;
            }
        }
    } else {
        // ---- V half: two 64-col LDS transpose passes -> coalesced Vt ----
        int no0 = n0 - INNERD;          // 0,128,256,384
        int h0  = no0 >> 6;             // head base (0,2,4,6)
        #pragma unroll
        for (int p = 0; p < 2; ++p) {
            __syncthreads();
            if ((wave & 1) == p) {      // waves with wn == p*64 own these cols
                #pragma unroll
                for (int mi = 0; mi < 4; ++mi)
                    #pragma unroll
                    for (int ni = 0; ni < 4; ++ni) {
                        int nl = ni * 16 + col;          // 0..63
                        int ml = wm + mi * 16 + quad * 4;
                        bf16x4 pk;
                        #pragma unroll
                        for (int rg = 0; rg < 4; ++rg) pk[rg] = (bfx)acc[mi][ni][rg];
                        *(bf16x4*)&Ts[nl * TST + ml] = pk;
                    }
            }
            __syncthreads();
            #pragma unroll
            for (int e = 0; e < 4; ++e) {
                int row = (tid >> 4) + e * 16;           // 0..63 = dd
                int chunk = tid & 15;
                bf16x8 v = *(const bf16x8*)&Ts[row * TST + chunk * 8];
                size_t rv = (size_t)(b * NH + h0 + p) * 2048 + rr * 64 + row;
                *(bf16x8*)&Vt[rv * SEQ + i0 + chunk * 8] = v;
            }
        }
    }
}

// ---------------- dots: per bh: S = Qr[512,2048] @ Kr^T --------------------
// XCD-swizzled: all 16 tiles of one bh share a dispatch-id residue (L2 reuse)
__global__ void dots_kernel(const bfx* __restrict__ Qr, const bfx* __restrict__ Kr,
                            float* __restrict__ Sbuf) {
    GEMM_PROLOGUE
    int flat = blockIdx.x + gridDim.x * (blockIdx.y + gridDim.y * blockIdx.z); // 0..255
    int bh   = (flat & 7) | (((flat >> 7) & 1) << 3);
    int tile = (flat >> 3) & 15;
    int m0 = (tile >> 2) * 128, n0 = (tile & 3) * 128;
    const bfx* A = Qr + (size_t)bh * SEQ * 2048;
    const bfx* B = Kr + (size_t)bh * SEQ * 2048;
    gemm_tile(A, 2048, B, 2048, m0, n0, 2048, As, Bs, acc);
    float* S = Sbuf + (size_t)bh * SEQ * SEQ;
    #pragma unroll
    for (int mi = 0; mi < 4; ++mi)
        #pragma unroll
        for (int ni = 0; ni < 4; ++ni)
            #pragma unroll
            for (int rg = 0; rg < 4; ++rg) {
                int i = m0 + wm + mi * 16 + quad * 4 + rg;
                int j = n0 + wn + ni * 16 + col;
                S[(size_t)i * SEQ + j] = acc[mi][ni][rg];
            }
}

// ---------------- softmax: Sbuf f32 -> Pb bf16 -----------------------------
__global__ void softmax_kernel(const int* __restrict__ m_any,
                               const float* __restrict__ Sbuf,
                               bfx* __restrict__ Pb) {
    int i = blockIdx.x, bh = blockIdx.y;
    int b = bh >> 3;
    const float* row = Sbuf + ((size_t)bh * SEQ + i) * SEQ;
    bfx* prow = Pb + ((size_t)bh * SEQ + i) * SEQ;
    const int* ma = m_any + b * SEQ;
    int fi = ma[i];
    int t = threadIdx.x;
    float v0 = (fi && ma[t])       ? row[t]       : -FLT_MAX;
    float v1 = (fi && ma[t + 256]) ? row[t + 256] : -FLT_MAX;
    __shared__ float red[256];
    red[t] = fmaxf(v0, v1);
    __syncthreads();
    for (int s = 128; s > 0; s >>= 1) {
        if (t < s) red[t] = fmaxf(red[t], red[t + s]);
        __syncthreads();
    }
    float mx = red[0];
    __syncthreads();
    float e0 = __expf(v0 - mx);
    float e1 = __expf(v1 - mx);
    red[t] = e0 + e1;
    __syncthreads();
    for (int s = 128; s > 0; s >>= 1) {
        if (t < s) red[t] += red[t + s];
        __syncthreads();
    }
    float inv = 1.0f / red[0];
    prow[t]       = (bfx)(e0 * inv);
    prow[t + 256] = (bfx)(e1 * inv);
}

// ---------------- PV: per bh: O[i,rd] = Pb[512,512] @ Vt[2048,512]^T -------
// epilogue: LDS re-tile -> 16B coalesced Obuf stores
__global__ void pv_kernel(const bfx* __restrict__ Pb, const bfx* __restrict__ Vt,
                          bfx* __restrict__ Obuf) {
    GEMM_PROLOGUE
    int bh = blockIdx.z;
    int b = bh >> 3, h = bh & 7;
    int m0 = blockIdx.y * 128, n0 = blockIdx.x * 128;
    const bfx* A = Pb + (size_t)bh * SEQ * SEQ;
    const bfx* B = Vt + (size_t)bh * 2048 * SEQ;
    gemm_tile(A, SEQ, B, SEQ, m0, n0, SEQ, As, Bs, acc);
    bfx* Ts = smem;
    #pragma unroll
    for (int p = 0; p < 2; ++p) {
        __syncthreads();
        if ((wave >> 1) == p) {
            #pragma unroll
            for (int mi = 0; mi < 4; ++mi)
                #pragma unroll
                for (int ni = 0; ni < 4; ++ni)
                    #pragma unroll
                    for (int rg = 0; rg < 4; ++rg) {
                        int rl = mi * 16 + quad * 4 + rg;
                        Ts[rl * TST + wn + ni * 16 + col] = (bfx)acc[mi][ni][rg];
                    }
        }
        __syncthreads();
        #pragma unroll
        for (int e = 0; e < 4; ++e) {
            int rl = (tid >> 4) + e * 16;
            int chunk = tid & 15;
            bf16x8 v = *(const bf16x8*)&Ts[rl * TST + chunk * 8];
            int i = m0 + p * 64 + rl;
            int rd = n0 + chunk * 8;
            int rr = rd >> 6, dd = rd & 63;
            *(bf16x8*)&Obuf[((size_t)((b * RT + rr) * SEQ + i)) * INNERD + h * DH + dd] = v;
        }
    }
}

// ---------------- out: Obuf[32768,512] @ woT^T + b_o -> f32 ----------------
__global__ void out_kernel(const bfx* __restrict__ A, const bfx* __restrict__ B,
                           const float* __restrict__ b_o, float* __restrict__ out) {
    GEMM_PROLOGUE
    int m0 = blockIdx.y * 128, n0 = blockIdx.x * 128;
    gemm_tile(A, INNERD, B, INNERD, m0, n0, INNERD, As, Bs, acc);
    #pragma unroll
    for (int mi = 0; mi < 4; ++mi)
        #pragma unroll
        for (int ni = 0; ni < 4; ++ni)
            #pragma unroll
            for (int rg = 0; rg < 4; ++rg) {
                int m = m0 + wm + mi * 16 + quad * 4 + rg;
                int c = n0 + wn + ni * 16 + col;
                out[(size_t)m * CDIM + c] = acc[mi][ni][rg] + b_o[c];
            }
}

// ---------------- workspace layout (bytes) — unchanged -------------
// 0         tab f32                                 131072
// 131072    m_any int32[1024]                         4096
// 135168    has_rows int32[64]                         256
// 135424    inv_nr f32 (+pad)                          256
// 135680    xb16 bf16 [8388608]   16777216   (REUSED: Sbuf f32 after kvgemm)
// 16912896  hdw  bf16 [8388608]   16777216   (REUSED: Pb bf16 after qgemm)
// 33690112  pw16 bf16                          262144
// 33952256  wkvT bf16                          524288
// 34476544  woT  bf16                          262144
// 34738688  Qr   bf16 [16777216]  33554432   (REUSED: Obuf after dots)
// 68293120  Kr   bf16 [16777216]  33554432
// 101847552 Vt   bf16 [16777216]  33554432
// end 135401984

extern "C" void kernel_launch(void* const* d_in, const int* in_sizes, int n_in,
                              void* d_out, int out_size, void* d_ws, size_t ws_size,
                              hipStream_t stream) {
    const float* x    = (const float*)d_in[0];
    const int*   mask = (const int*)d_in[1];
    const float* dw_w = (const float*)d_in[3];
    const float* dw_b = (const float*)d_in[4];
    const float* pw_w = (const float*)d_in[5];
    const float* pw_b = (const float*)d_in[6];
    const float* w_kv = (const float*)d_in[7];
    const float* w_o  = (const float*)d_in[8];
    const float* b_o  = (const float*)d_in[9];
    float* out = (float*)d_out;

    char* ws = (char*)d_ws;
    float* tab   = (float*)(ws + 0);
    int*   m_any = (int*)(ws + 131072);
    int*   hrows = (int*)(ws + 135168);
    float* invnr = (float*)(ws + 135424);
    bfx*   xb16  = (bfx*)(ws + 135680);
    float* Sbuf  = (float*)(ws + 135680);      // alias xb16 (dead after kvgemm)
    bfx*   hdw   = (bfx*)(ws + 16912896);
    bfx*   Pb    = (bfx*)(ws + 16912896);      // alias hdw (dead after qgemm)
    bfx*   pw16  = (bfx*)(ws + 33690112);
    bfx*   wkvT  = (bfx*)(ws + 33952256);
    bfx*   woT   = (bfx*)(ws + 34476544);
    bfx*   Qr    = (bfx*)(ws + 34738688);
    bfx*   Obuf  = (bfx*)(ws + 34738688);      // alias Qr (dead after dots)
    bfx*   Kr    = (bfx*)(ws + 68293120);
    bfx*   Vt    = (bfx*)(ws + 101847552);

    if (ws_size < 135401984u) return;

    hipLaunchKernelGGL(prep_kernel,  dim3(9922),      dim3(256), 0, stream,
                       x, pw_w, w_kv, w_o, mask, xb16, pw16, wkvT, woT,
                       tab, m_any, hrows, invnr);
    hipLaunchKernelGGL(conv_kernel,  dim3(64, 8),     dim3(256), 0, stream, xb16, dw_w, dw_b, hdw);
    hipLaunchKernelGGL(qgemm_kernel, dim3(4, 256),    dim3(256), 0, stream, hdw, pw16, pw_b, hrows, invnr, tab, Qr);
    hipLaunchKernelGGL(kvgemm_kernel,dim3(8, 256),    dim3(256), 0, stream, xb16, wkvT, tab, Kr, Vt);
    hipLaunchKernelGGL(dots_kernel,  dim3(4, 4, 16),  dim3(256), 0, stream, Qr, Kr, Sbuf);
    hipLaunchKernelGGL(softmax_kernel, dim3(SEQ, 16), dim3(256), 0, stream, m_any, Sbuf, Pb);
    hipLaunchKernelGGL(pv_kernel,    dim3(16, 4, 16), dim3(256), 0, stream, Pb, Vt, Obuf);
    hipLaunchKernelGGL(out_kernel,   dim3(2, 256),    dim3(256), 0, stream, Obuf, woT, b_o, out);
}

// Round 7
// 283.214 us; speedup vs baseline: 1.2112x; 1.2112x over previous
//
#include <hip/hip_runtime.h>
#include <hip/hip_bf16.h>
#include <float.h>
#include <math.h>

typedef __bf16 bfx;
typedef __attribute__((ext_vector_type(8))) __bf16 bf16x8;
typedef __attribute__((ext_vector_type(4))) __bf16 bf16x4;
typedef __attribute__((ext_vector_type(2))) __bf16 bf16x2;
typedef __attribute__((ext_vector_type(4))) float f32x4;

#define SEQ    512
#define CDIM   256
#define NH     8
#define DH     64
#define INNERD 512
#define RT     32
#define NB     2
#define KW     15
#define PW     7
#define LDT    40   // padded LDS row stride (bf16): 80B rows -> <=2-way conflicts
#define TST    136  // V-transpose stage stride (bf16): 272B, 16B-aligned

// ================= fused prep: cvt x, sincos, cvt pw, tcvt wkv/wo, mask ====
__global__ void prep_kernel(const float* __restrict__ x,
                            const float* __restrict__ pw_w,
                            const float* __restrict__ w_kv,
                            const float* __restrict__ w_o,
                            const int*   __restrict__ mask,
                            bfx* __restrict__ xb16, bfx* __restrict__ pw16,
                            bfx* __restrict__ wkvT, bfx* __restrict__ woT,
                            float* __restrict__ tab,
                            int* __restrict__ m_any, int* __restrict__ has_rows,
                            float* __restrict__ inv_nr) {
    int bid = blockIdx.x, tid = threadIdx.x;
    if (bid < 8192) {                       // x -> bf16, 4 elems/thread
        int idx = bid * 256 + tid;
        float4 v = ((const float4*)x)[idx];
        bfx* d = xb16 + idx * 4;
        d[0] = (bfx)v.x; d[1] = (bfx)v.y; d[2] = (bfx)v.z; d[3] = (bfx)v.w;
        return;
    }
    int b2 = bid - 8192;
    if (b2 < 64) {                          // sincos table
        int idx = b2 * 256 + tid;
        int i = idx >> 5, j = idx & 31;
        float inv_freq = powf(10000.0f, -(float)j / 32.0f);
        float s, c;
        sincosf((float)i * inv_freq, &s, &c);
        tab[idx * 2] = s; tab[idx * 2 + 1] = c;
        return;
    }
    b2 -= 64;
    if (b2 < 128) {                         // pw_w -> bf16 (already [n][k])
        int idx = b2 * 256 + tid;
        float4 v = ((const float4*)pw_w)[idx];
        bfx* d = pw16 + idx * 4;
        d[0] = (bfx)v.x; d[1] = (bfx)v.y; d[2] = (bfx)v.z; d[3] = (bfx)v.w;
        return;
    }
    b2 -= 128;
    if (b2 < 1024) {                        // w_kv transpose: wkvT[n*256+k]
        int idx = b2 * 256 + tid;
        int k = idx & 255, n = idx >> 8;
        wkvT[idx] = (bfx)w_kv[(size_t)k * 1024 + n];
        return;
    }
    b2 -= 1024;
    if (b2 < 512) {                         // w_o transpose: woT[n*512+k]
        int idx = b2 * 256 + tid;
        int k = idx & 511, n = idx >> 9;
        woT[idx] = (bfx)w_o[(size_t)k * CDIM + n];
        return;
    }
    b2 -= 512;
    {                                       // mask stats, b = b2 (0..1)
        int b = b2;
        #pragma unroll
        for (int half = 0; half < 2; ++half) {
            int i = tid + half * 256;
            int any_col = 0;
            for (int rr = 0; rr < RT; ++rr)
                any_col |= mask[(size_t)(b * RT + rr) * SEQ + i];
            m_any[b * SEQ + i] = any_col ? 1 : 0;
        }
        __shared__ int hr[RT];
        if (tid < RT) {
            int a = 0;
            const int* mrow = mask + (size_t)(b * RT + tid) * SEQ;
            for (int j = 0; j < SEQ; ++j) a |= mrow[j];
            hr[tid] = a ? 1 : 0;
            has_rows[b * RT + tid] = hr[tid];
        }
        __syncthreads();
        if (tid == 0) {
            int s = 0;
            for (int rr = 0; rr < RT; ++rr) s += hr[rr];
            inv_nr[b] = (s > 0) ? rsqrtf((float)s) : 0.0f;
        }
    }
}

// ---------------- depthwise conv1d: 2 ch/thread, 32-row chunks -------------
__global__ void conv_kernel(const bfx* __restrict__ xb,
                            const float* __restrict__ dw_w,
                            const float* __restrict__ dw_b,
                            bfx* __restrict__ hdw) {
    int bn  = blockIdx.x;
    int grp = threadIdx.x >> 7;
    int t   = threadIdx.x & 127;
    int i0  = blockIdx.y * 64 + grp * 32;
    int c   = t * 2;
    const bf16x2* xc = (const bf16x2*)(xb + (size_t)bn * SEQ * CDIM) + t;
    float w0[KW], w1[KW];
    #pragma unroll
    for (int k = 0; k < KW; ++k) { w0[k] = dw_w[c * KW + k]; w1[k] = dw_w[(c + 1) * KW + k]; }
    float b0 = dw_b[c], b1 = dw_b[c + 1];
    float win0[KW], win1[KW];
    #pragma unroll
    for (int k = 0; k < KW; ++k) {
        int p = i0 - PW + k;
        if (p >= 0 && p < SEQ) {
            bf16x2 v = xc[(size_t)p * 128];
            win0[k] = (float)v[0]; win1[k] = (float)v[1];
        } else { win0[k] = 0.0f; win1[k] = 0.0f; }
    }
    bf16x2* orow = (bf16x2*)(hdw + ((size_t)bn * SEQ + i0) * CDIM) + t;
    for (int i = i0; i < i0 + 32; ++i) {
        float a0 = b0, a1 = b1;
        #pragma unroll
        for (int k = 0; k < KW; ++k) { a0 += win0[k] * w0[k]; a1 += win1[k] * w1[k]; }
        bf16x2 o; o[0] = (bfx)a0; o[1] = (bfx)a1;
        *orow = o;
        orow += 128;
        #pragma unroll
        for (int k = 0; k < KW - 1; ++k) { win0[k] = win0[k + 1]; win1[k] = win1[k + 1]; }
        int p = i + PW + 1;
        if (p < SEQ) {
            bf16x2 v = xc[(size_t)p * 128];
            win0[KW - 1] = (float)v[0]; win1[KW - 1] = (float)v[1];
        } else { win0[KW - 1] = 0.0f; win1[KW - 1] = 0.0f; }
    }
}

// ---------------- shared 128x128 MFMA tile ---------------------------------
__device__ __forceinline__ void gemm_tile(const bfx* __restrict__ A, int lda,
                                          const bfx* __restrict__ B, int ldb,
                                          int m0, int n0, int K,
                                          bfx* As, bfx* Bs, f32x4 acc[4][4]) {
    int tid = threadIdx.x;
    int wave = tid >> 6, lane = tid & 63;
    int wm = (wave >> 1) * 64, wn = (wave & 1) * 64;
    int col = lane & 15, quad = lane >> 4;
    for (int k0 = 0; k0 < K; k0 += 32) {
        #pragma unroll
        for (int r = 0; r < 2; ++r) {
            int v = tid + r * 256;
            int row = v >> 2, kv = (v & 3) * 8;
            *(bf16x8*)&As[row * LDT + kv] = *(const bf16x8*)&A[(size_t)(m0 + row) * lda + k0 + kv];
            *(bf16x8*)&Bs[row * LDT + kv] = *(const bf16x8*)&B[(size_t)(n0 + row) * ldb + k0 + kv];
        }
        __syncthreads();
        bf16x8 af[4], bff[4];
        #pragma unroll
        for (int f = 0; f < 4; ++f) {
            af[f]  = *(const bf16x8*)&As[(wm + f * 16 + col) * LDT + quad * 8];
            bff[f] = *(const bf16x8*)&Bs[(wn + f * 16 + col) * LDT + quad * 8];
        }
        #pragma unroll
        for (int mi = 0; mi < 4; ++mi)
            #pragma unroll
            for (int ni = 0; ni < 4; ++ni)
                acc[mi][ni] = __builtin_amdgcn_mfma_f32_16x16x32_bf16(af[mi], bff[ni], acc[mi][ni], 0, 0, 0);
        __syncthreads();
    }
}

#define GEMM_PROLOGUE \
    __shared__ __align__(16) bfx smem[2 * 128 * LDT]; \
    bfx* As = smem; bfx* Bs = smem + 128 * LDT; \
    f32x4 acc[4][4]; \
    _Pragma("unroll") for (int i_ = 0; i_ < 4; ++i_) \
    _Pragma("unroll") for (int j_ = 0; j_ < 4; ++j_) acc[i_][j_] = (f32x4){0.f, 0.f, 0.f, 0.f}; \
    int tid = threadIdx.x; \
    int wave = tid >> 6, lane = tid & 63; \
    int wm = (wave >> 1) * 64, wn = (wave & 1) * 64; \
    int col = lane & 15, quad = lane >> 4;

// ---------------- q GEMM: hdw[32768,256] @ pw16^T -> rotary -> Qr ----------
// 1-D grid 1024, XCD swizzle: stripe y -> blocks with id%8 == y%8 (one XCD)
__global__ void qgemm_kernel(const bfx* __restrict__ A, const bfx* __restrict__ B,
                             const float* __restrict__ pw_b,
                             const int* __restrict__ has_rows,
                             const float* __restrict__ inv_nr,
                             const float* __restrict__ tab,
                             bfx* __restrict__ Qr) {
    GEMM_PROLOGUE
    int g = blockIdx.x;
    int y = ((g >> 5) << 3) | (g & 7);     // 0..255
    int xt = (g >> 3) & 3;                 // 0..3
    int m0 = y * 128, n0 = xt * 128;
    gemm_tile(A, CDIM, B, CDIM, m0, n0, CDIM, As, Bs, acc);
    int bn = m0 >> 9, b = bn >> 5, rr = bn & 31;
    float zs = has_rows[bn] ? 0.125f * inv_nr[b] : 0.0f;
    #pragma unroll
    for (int mi = 0; mi < 4; ++mi)
        #pragma unroll
        for (int ni = 0; ni < 4; ++ni)
            #pragma unroll
            for (int rg = 0; rg < 4; ++rg) {
                int m = m0 + wm + mi * 16 + quad * 4 + rg;
                int i = m & (SEQ - 1);
                int o = n0 + wn + ni * 16 + col;
                float v  = acc[mi][ni][rg];
                float vp = __shfl_xor(v, 1);
                float q  = v + pw_b[o];
                float qp = vp + pw_b[o ^ 1];
                int h = o >> 6, dd = o & 63, j = dd >> 1;
                float sn = tab[(i * 32 + j) * 2], cs = tab[(i * 32 + j) * 2 + 1];
                float r = (o & 1) ? (q * cs + qp * sn) : (q * cs - qp * sn);
                Qr[((size_t)((b * NH + h) * SEQ + i)) * 2048 + rr * 64 + dd] = (bfx)(r * zs);
            }
}

// ---------------- kv GEMM: xb[32768,256] @ wkvT^T ---------------------------
// 1-D grid 2048, XCD swizzle. xt<4: K half -> rotary -> Kr; xt>=4: V half ->
// LDS transpose -> coalesced Vt[bh][rd][i] stores.
__global__ void kvgemm_kernel(const bfx* __restrict__ A, const bfx* __restrict__ B,
                              const float* __restrict__ tab,
                              bfx* __restrict__ Kr, bfx* __restrict__ Vt) {
    GEMM_PROLOGUE
    int g = blockIdx.x;
    int y = ((g >> 6) << 3) | (g & 7);     // 0..255
    int xt = (g >> 3) & 7;                 // 0..7
    int m0 = y * 128, n0 = xt * 128;
    gemm_tile(A, CDIM, B, CDIM, m0, n0, CDIM, As, Bs, acc);
    int bn = m0 >> 9, b = bn >> 5, rr = bn & 31;
    if (xt < 4) {
        // ---- K half: rotary epilogue, direct 32B-segment stores ----
        #pragma unroll
        for (int mi = 0; mi < 4; ++mi)
            #pragma unroll
            for (int ni = 0; ni < 4; ++ni)
                #pragma unroll
                for (int rg = 0; rg < 4; ++rg) {
                    int m = m0 + wm + mi * 16 + quad * 4 + rg;
                    int i = m & (SEQ - 1);
                    int o = n0 + wn + ni * 16 + col;
                    float v  = acc[mi][ni][rg];
                    float vp = __shfl_xor(v, 1);
                    int h = o >> 6, dd = o & 63, j = dd >> 1;
                    float sn = tab[(i * 32 + j) * 2], cs = tab[(i * 32 + j) * 2 + 1];
                    float r = (o & 1) ? (v * cs + vp * sn) : (v * cs - vp * sn);
                    Kr[((size_t)((b * NH + h) * SEQ + i)) * 2048 + rr * 64 + dd] = (bfx)r;
                }
    } else {
        // ---- V half: two 64-col LDS transpose passes -> coalesced Vt ----
        int no0 = n0 - INNERD;          // 0,128,256,384
        int h0  = no0 >> 6;             // head base (0,2,4,6)
        int i0  = m0 & (SEQ - 1);
        bfx* Ts = smem;                 // 64 x TST bf16 = 17408 B <= 20480 B
        #pragma unroll
        for (int p = 0; p < 2; ++p) {
            __syncthreads();
            if ((wave & 1) == p) {      // waves with wn == p*64 own these cols
                #pragma unroll
                for (int mi = 0; mi < 4; ++mi)
                    #pragma unroll
                    for (int ni = 0; ni < 4; ++ni) {
                        int nl = ni * 16 + col;          // 0..63
                        int ml = wm + mi * 16 + quad * 4;
                        bf16x4 pk;
                        #pragma unroll
                        for (int rg = 0; rg < 4; ++rg) pk[rg] = (bfx)acc[mi][ni][rg];
                        *(bf16x4*)&Ts[nl * TST + ml] = pk;
                    }
            }
            __syncthreads();
            #pragma unroll
            for (int e = 0; e < 4; ++e) {
                int row = (tid >> 4) + e * 16;           // 0..63 = dd
                int chunk = tid & 15;
                bf16x8 v = *(const bf16x8*)&Ts[row * TST + chunk * 8];
                size_t rv = (size_t)(b * NH + h0 + p) * 2048 + rr * 64 + row;
                *(bf16x8*)&Vt[rv * SEQ + i0 + chunk * 8] = v;
            }
        }
    }
}

// ---------------- dots: per bh: S = Qr[512,2048] @ Kr^T --------------------
// 1-D grid 256, XCD swizzle: all 16 tiles of one bh share id%8 (one XCD)
__global__ void dots_kernel(const bfx* __restrict__ Qr, const bfx* __restrict__ Kr,
                            float* __restrict__ Sbuf) {
    GEMM_PROLOGUE
    int g = blockIdx.x;                    // 0..255
    int bh   = (g & 7) | (((g >> 7) & 1) << 3);
    int tile = (g >> 3) & 15;
    int m0 = (tile >> 2) * 128, n0 = (tile & 3) * 128;
    const bfx* A = Qr + (size_t)bh * SEQ * 2048;
    const bfx* B = Kr + (size_t)bh * SEQ * 2048;
    gemm_tile(A, 2048, B, 2048, m0, n0, 2048, As, Bs, acc);
    float* S = Sbuf + (size_t)bh * SEQ * SEQ;
    #pragma unroll
    for (int mi = 0; mi < 4; ++mi)
        #pragma unroll
        for (int ni = 0; ni < 4; ++ni)
            #pragma unroll
            for (int rg = 0; rg < 4; ++rg) {
                int i = m0 + wm + mi * 16 + quad * 4 + rg;
                int j = n0 + wn + ni * 16 + col;
                S[(size_t)i * SEQ + j] = acc[mi][ni][rg];
            }
}

// ---------------- softmax: Sbuf f32 -> Pb bf16 -----------------------------
__global__ void softmax_kernel(const int* __restrict__ m_any,
                               const float* __restrict__ Sbuf,
                               bfx* __restrict__ Pb) {
    int i = blockIdx.x, bh = blockIdx.y;
    int b = bh >> 3;
    const float* row = Sbuf + ((size_t)bh * SEQ + i) * SEQ;
    bfx* prow = Pb + ((size_t)bh * SEQ + i) * SEQ;
    const int* ma = m_any + b * SEQ;
    int fi = ma[i];
    int t = threadIdx.x;
    float v0 = (fi && ma[t])       ? row[t]       : -FLT_MAX;
    float v1 = (fi && ma[t + 256]) ? row[t + 256] : -FLT_MAX;
    __shared__ float red[256];
    red[t] = fmaxf(v0, v1);
    __syncthreads();
    for (int s = 128; s > 0; s >>= 1) {
        if (t < s) red[t] = fmaxf(red[t], red[t + s]);
        __syncthreads();
    }
    float mx = red[0];
    __syncthreads();
    float e0 = __expf(v0 - mx);
    float e1 = __expf(v1 - mx);
    red[t] = e0 + e1;
    __syncthreads();
    for (int s = 128; s > 0; s >>= 1) {
        if (t < s) red[t] += red[t + s];
        __syncthreads();
    }
    float inv = 1.0f / red[0];
    prow[t]       = (bfx)(e0 * inv);
    prow[t + 256] = (bfx)(e1 * inv);
}

// ---------------- PV: per bh: O[i,rd] = Pb[512,512] @ Vt[2048,512]^T -------
// 1-D grid 1024, XCD swizzle: all 64 tiles of one bh share id%8 (one XCD)
__global__ void pv_kernel(const bfx* __restrict__ Pb, const bfx* __restrict__ Vt,
                          bfx* __restrict__ Obuf) {
    GEMM_PROLOGUE
    int g = blockIdx.x;                    // 0..1023
    int bh   = (g & 7) | (((g >> 9) & 1) << 3);
    int tile = (g >> 3) & 63;
    int m0 = (tile >> 4) * 128, n0 = (tile & 15) * 128;  // wait: 16 x-tiles? no: 16 rd-tiles? rd=2048/128=16, i=512/128=4
    int b = bh >> 3, h = bh & 7;
    const bfx* A = Pb + (size_t)bh * SEQ * SEQ;
    const bfx* B = Vt + (size_t)bh * 2048 * SEQ;
    gemm_tile(A, SEQ, B, SEQ, m0, n0, SEQ, As, Bs, acc);
    #pragma unroll
    for (int mi = 0; mi < 4; ++mi)
        #pragma unroll
        for (int ni = 0; ni < 4; ++ni)
            #pragma unroll
            for (int rg = 0; rg < 4; ++rg) {
                int i = m0 + wm + mi * 16 + quad * 4 + rg;
                int rd = n0 + wn + ni * 16 + col;
                int rr = rd >> 6, dd = rd & 63;
                Obuf[((size_t)((b * RT + rr) * SEQ + i)) * INNERD + h * DH + dd] =
                    (bfx)acc[mi][ni][rg];
            }
}

// ---------------- out: Obuf[32768,512] @ woT^T + b_o -> f32 ----------------
// 1-D grid 512, XCD swizzle
__global__ void out_kernel(const bfx* __restrict__ A, const bfx* __restrict__ B,
                           const float* __restrict__ b_o, float* __restrict__ out) {
    GEMM_PROLOGUE
    int g = blockIdx.x;
    int y = ((g >> 4) << 3) | (g & 7);     // 0..255
    int xt = (g >> 3) & 1;
    int m0 = y * 128, n0 = xt * 128;
    gemm_tile(A, INNERD, B, INNERD, m0, n0, INNERD, As, Bs, acc);
    #pragma unroll
    for (int mi = 0; mi < 4; ++mi)
        #pragma unroll
        for (int ni = 0; ni < 4; ++ni)
            #pragma unroll
            for (int rg = 0; rg < 4; ++rg) {
                int m = m0 + wm + mi * 16 + quad * 4 + rg;
                int c = n0 + wn + ni * 16 + col;
                out[(size_t)m * CDIM + c] = acc[mi][ni][rg] + b_o[c];
            }
}

// ---------------- workspace layout (bytes) — unchanged -------------
// 0         tab f32                                 131072
// 131072    m_any int32[1024]                         4096
// 135168    has_rows int32[64]                         256
// 135424    inv_nr f32 (+pad)                          256
// 135680    xb16 bf16 [8388608]   16777216   (REUSED: Sbuf f32 after kvgemm)
// 16912896  hdw  bf16 [8388608]   16777216   (REUSED: Pb bf16 after qgemm)
// 33690112  pw16 bf16                          262144
// 33952256  wkvT bf16                          524288
// 34476544  woT  bf16                          262144
// 34738688  Qr   bf16 [16777216]  33554432   (REUSED: Obuf after dots)
// 68293120  Kr   bf16 [16777216]  33554432
// 101847552 Vt   bf16 [16777216]  33554432
// end 135401984

extern "C" void kernel_launch(void* const* d_in, const int* in_sizes, int n_in,
                              void* d_out, int out_size, void* d_ws, size_t ws_size,
                              hipStream_t stream) {
    const float* x    = (const float*)d_in[0];
    const int*   mask = (const int*)d_in[1];
    const float* dw_w = (const float*)d_in[3];
    const float* dw_b = (const float*)d_in[4];
    const float* pw_w = (const float*)d_in[5];
    const float* pw_b = (const float*)d_in[6];
    const float* w_kv = (const float*)d_in[7];
    const float* w_o  = (const float*)d_in[8];
    const float* b_o  = (const float*)d_in[9];
    float* out = (float*)d_out;

    char* ws = (char*)d_ws;
    float* tab   = (float*)(ws + 0);
    int*   m_any = (int*)(ws + 131072);
    int*   hrows = (int*)(ws + 135168);
    float* invnr = (float*)(ws + 135424);
    bfx*   xb16  = (bfx*)(ws + 135680);
    float* Sbuf  = (float*)(ws + 135680);      // alias xb16 (dead after kvgemm)
    bfx*   hdw   = (bfx*)(ws + 16912896);
    bfx*   Pb    = (bfx*)(ws + 16912896);      // alias hdw (dead after qgemm)
    bfx*   pw16  = (bfx*)(ws + 33690112);
    bfx*   wkvT  = (bfx*)(ws + 33952256);
    bfx*   woT   = (bfx*)(ws + 34476544);
    bfx*   Qr    = (bfx*)(ws + 34738688);
    bfx*   Obuf  = (bfx*)(ws + 34738688);      // alias Qr (dead after dots)
    bfx*   Kr    = (bfx*)(ws + 68293120);
    bfx*   Vt    = (bfx*)(ws + 101847552);

    if (ws_size < 135401984u) return;

    hipLaunchKernelGGL(prep_kernel,  dim3(9922),    dim3(256), 0, stream,
                       x, pw_w, w_kv, w_o, mask, xb16, pw16, wkvT, woT,
                       tab, m_any, hrows, invnr);
    hipLaunchKernelGGL(conv_kernel,  dim3(64, 8),   dim3(256), 0, stream, xb16, dw_w, dw_b, hdw);
    hipLaunchKernelGGL(qgemm_kernel, dim3(1024),    dim3(256), 0, stream, hdw, pw16, pw_b, hrows, invnr, tab, Qr);
    hipLaunchKernelGGL(kvgemm_kernel,dim3(2048),    dim3(256), 0, stream, xb16, wkvT, tab, Kr, Vt);
    hipLaunchKernelGGL(dots_kernel,  dim3(256),     dim3(256), 0, stream, Qr, Kr, Sbuf);
    hipLaunchKernelGGL(softmax_kernel, dim3(SEQ, 16), dim3(256), 0, stream, m_any, Sbuf, Pb);
    hipLaunchKernelGGL(pv_kernel,    dim3(1024),    dim3(256), 0, stream, Pb, Vt, Obuf);
    hipLaunchKernelGGL(out_kernel,   dim3(512),     dim3(256), 0, stream, Obuf, woT, b_o, out);
}

// Round 9
// 272.351 us; speedup vs baseline: 1.2595x; 1.0399x over previous
//
#include <hip/hip_runtime.h>
#include <hip/hip_bf16.h>
#include <float.h>
#include <math.h>

typedef __bf16 bfx;
typedef __attribute__((ext_vector_type(8))) __bf16 bf16x8;
typedef __attribute__((ext_vector_type(4))) __bf16 bf16x4;
typedef __attribute__((ext_vector_type(2))) __bf16 bf16x2;
typedef __attribute__((ext_vector_type(4))) float f32x4;

#define SEQ    512
#define CDIM   256
#define NH     8
#define DH     64
#define INNERD 512
#define RT     32
#define NB     2
#define KW     15
#define PW     7
#define LDT    40   // padded LDS row stride (bf16): 80B rows -> <=2-way conflicts
#define TST    136  // V-transpose stage stride (bf16): 272B, 16B-aligned

// ================= fused prep: cvt x, sincos, cvt pw, tcvt wkv/wo, mask ====
__global__ void prep_kernel(const float* __restrict__ x,
                            const float* __restrict__ pw_w,
                            const float* __restrict__ w_kv,
                            const float* __restrict__ w_o,
                            const int*   __restrict__ mask,
                            bfx* __restrict__ xb16, bfx* __restrict__ pw16,
                            bfx* __restrict__ wkvT, bfx* __restrict__ woT,
                            float* __restrict__ tab,
                            int* __restrict__ m_any, int* __restrict__ has_rows,
                            float* __restrict__ inv_nr) {
    int bid = blockIdx.x, tid = threadIdx.x;
    if (bid < 8192) {                       // x -> bf16, 4 elems/thread
        int idx = bid * 256 + tid;
        float4 v = ((const float4*)x)[idx];
        bfx* d = xb16 + idx * 4;
        d[0] = (bfx)v.x; d[1] = (bfx)v.y; d[2] = (bfx)v.z; d[3] = (bfx)v.w;
        return;
    }
    int b2 = bid - 8192;
    if (b2 < 64) {                          // sincos table
        int idx = b2 * 256 + tid;
        int i = idx >> 5, j = idx & 31;
        float inv_freq = powf(10000.0f, -(float)j / 32.0f);
        float s, c;
        sincosf((float)i * inv_freq, &s, &c);
        tab[idx * 2] = s; tab[idx * 2 + 1] = c;
        return;
    }
    b2 -= 64;
    if (b2 < 128) {                         // pw_w -> bf16 (already [n][k])
        int idx = b2 * 256 + tid;
        float4 v = ((const float4*)pw_w)[idx];
        bfx* d = pw16 + idx * 4;
        d[0] = (bfx)v.x; d[1] = (bfx)v.y; d[2] = (bfx)v.z; d[3] = (bfx)v.w;
        return;
    }
    b2 -= 128;
    if (b2 < 1024) {                        // w_kv transpose: wkvT[n*256+k]
        int idx = b2 * 256 + tid;
        int k = idx & 255, n = idx >> 8;
        wkvT[idx] = (bfx)w_kv[(size_t)k * 1024 + n];
        return;
    }
    b2 -= 1024;
    if (b2 < 512) {                         // w_o transpose: woT[n*512+k]
        int idx = b2 * 256 + tid;
        int k = idx & 511, n = idx >> 9;
        woT[idx] = (bfx)w_o[(size_t)k * CDIM + n];
        return;
    }
    b2 -= 512;
    {                                       // mask stats, b = b2 (0..1)
        int b = b2;
        #pragma unroll
        for (int half = 0; half < 2; ++half) {
            int i = tid + half * 256;
            int any_col = 0;
            for (int rr = 0; rr < RT; ++rr)
                any_col |= mask[(size_t)(b * RT + rr) * SEQ + i];
            m_any[b * SEQ + i] = any_col ? 1 : 0;
        }
        __shared__ int hr[RT];
        if (tid < RT) {
            int a = 0;
            const int* mrow = mask + (size_t)(b * RT + tid) * SEQ;
            for (int j = 0; j < SEQ; ++j) a |= mrow[j];
            hr[tid] = a ? 1 : 0;
            has_rows[b * RT + tid] = hr[tid];
        }
        __syncthreads();
        if (tid == 0) {
            int s = 0;
            for (int rr = 0; rr < RT; ++rr) s += hr[rr];
            inv_nr[b] = (s > 0) ? rsqrtf((float)s) : 0.0f;
        }
    }
}

// ---------------- depthwise conv1d: 2 ch/thread, 32-row chunks -------------
__global__ void conv_kernel(const bfx* __restrict__ xb,
                            const float* __restrict__ dw_w,
                            const float* __restrict__ dw_b,
                            bfx* __restrict__ hdw) {
    int bn  = blockIdx.x;
    int grp = threadIdx.x >> 7;
    int t   = threadIdx.x & 127;
    int i0  = blockIdx.y * 64 + grp * 32;
    int c   = t * 2;
    const bf16x2* xc = (const bf16x2*)(xb + (size_t)bn * SEQ * CDIM) + t;
    float w0[KW], w1[KW];
    #pragma unroll
    for (int k = 0; k < KW; ++k) { w0[k] = dw_w[c * KW + k]; w1[k] = dw_w[(c + 1) * KW + k]; }
    float b0 = dw_b[c], b1 = dw_b[c + 1];
    float win0[KW], win1[KW];
    #pragma unroll
    for (int k = 0; k < KW; ++k) {
        int p = i0 - PW + k;
        if (p >= 0 && p < SEQ) {
            bf16x2 v = xc[(size_t)p * 128];
            win0[k] = (float)v[0]; win1[k] = (float)v[1];
        } else { win0[k] = 0.0f; win1[k] = 0.0f; }
    }
    bf16x2* orow = (bf16x2*)(hdw + ((size_t)bn * SEQ + i0) * CDIM) + t;
    for (int i = i0; i < i0 + 32; ++i) {
        float a0 = b0, a1 = b1;
        #pragma unroll
        for (int k = 0; k < KW; ++k) { a0 += win0[k] * w0[k]; a1 += win1[k] * w1[k]; }
        bf16x2 o; o[0] = (bfx)a0; o[1] = (bfx)a1;
        *orow = o;
        orow += 128;
        #pragma unroll
        for (int k = 0; k < KW - 1; ++k) { win0[k] = win0[k + 1]; win1[k] = win1[k + 1]; }
        int p = i + PW + 1;
        if (p < SEQ) {
            bf16x2 v = xc[(size_t)p * 128];
            win0[KW - 1] = (float)v[0]; win1[KW - 1] = (float)v[1];
        } else { win0[KW - 1] = 0.0f; win1[KW - 1] = 0.0f; }
    }
}

// ---------------- shared 128x128 MFMA tile ---------------------------------
__device__ __forceinline__ void gemm_tile(const bfx* __restrict__ A, int lda,
                                          const bfx* __restrict__ B, int ldb,
                                          int m0, int n0, int K,
                                          bfx* As, bfx* Bs, f32x4 acc[4][4]) {
    int tid = threadIdx.x;
    int wave = tid >> 6, lane = tid & 63;
    int wm = (wave >> 1) * 64, wn = (wave & 1) * 64;
    int col = lane & 15, quad = lane >> 4;
    for (int k0 = 0; k0 < K; k0 += 32) {
        #pragma unroll
        for (int r = 0; r < 2; ++r) {
            int v = tid + r * 256;
            int row = v >> 2, kv = (v & 3) * 8;
            *(bf16x8*)&As[row * LDT + kv] = *(const bf16x8*)&A[(size_t)(m0 + row) * lda + k0 + kv];
            *(bf16x8*)&Bs[row * LDT + kv] = *(const bf16x8*)&B[(size_t)(n0 + row) * ldb + k0 + kv];
        }
        __syncthreads();
        bf16x8 af[4], bff[4];
        #pragma unroll
        for (int f = 0; f < 4; ++f) {
            af[f]  = *(const bf16x8*)&As[(wm + f * 16 + col) * LDT + quad * 8];
            bff[f] = *(const bf16x8*)&Bs[(wn + f * 16 + col) * LDT + quad * 8];
        }
        #pragma unroll
        for (int mi = 0; mi < 4; ++mi)
            #pragma unroll
            for (int ni = 0; ni < 4; ++ni)
                acc[mi][ni] = __builtin_amdgcn_mfma_f32_16x16x32_bf16(af[mi], bff[ni], acc[mi][ni], 0, 0, 0);
        __syncthreads();
    }
}

#define GEMM_PROLOGUE \
    __shared__ __align__(16) bfx smem[2 * 128 * LDT]; \
    bfx* As = smem; bfx* Bs = smem + 128 * LDT; \
    f32x4 acc[4][4]; \
    _Pragma("unroll") for (int i_ = 0; i_ < 4; ++i_) \
    _Pragma("unroll") for (int j_ = 0; j_ < 4; ++j_) acc[i_][j_] = (f32x4){0.f, 0.f, 0.f, 0.f}; \
    int tid = threadIdx.x; \
    int wave = tid >> 6, lane = tid & 63; \
    int wm = (wave >> 1) * 64, wn = (wave & 1) * 64; \
    int col = lane & 15, quad = lane >> 4;

// ---------------- q GEMM: hdw[32768,256] @ pw16^T -> rotary -> Qr ----------
// 1-D grid 1024, XCD swizzle: stripe y -> blocks with id%8 == y%8 (one XCD)
__global__ void qgemm_kernel(const bfx* __restrict__ A, const bfx* __restrict__ B,
                             const float* __restrict__ pw_b,
                             const int* __restrict__ has_rows,
                             const float* __restrict__ inv_nr,
                             const float* __restrict__ tab,
                             bfx* __restrict__ Qr) {
    GEMM_PROLOGUE
    int g = blockIdx.x;
    int y = ((g >> 5) << 3) | (g & 7);     // 0..255
    int xt = (g >> 3) & 3;                 // 0..3
    int m0 = y * 128, n0 = xt * 128;
    gemm_tile(A, CDIM, B, CDIM, m0, n0, CDIM, As, Bs, acc);
    int bn = m0 >> 9, b = bn >> 5, rr = bn & 31;
    float zs = has_rows[bn] ? 0.125f * inv_nr[b] : 0.0f;
    #pragma unroll
    for (int mi = 0; mi < 4; ++mi)
        #pragma unroll
        for (int ni = 0; ni < 4; ++ni)
            #pragma unroll
            for (int rg = 0; rg < 4; ++rg) {
                int m = m0 + wm + mi * 16 + quad * 4 + rg;
                int i = m & (SEQ - 1);
                int o = n0 + wn + ni * 16 + col;
                float v  = acc[mi][ni][rg];
                float vp = __shfl_xor(v, 1);
                float q  = v + pw_b[o];
                float qp = vp + pw_b[o ^ 1];
                int h = o >> 6, dd = o & 63, j = dd >> 1;
                float sn = tab[(i * 32 + j) * 2], cs = tab[(i * 32 + j) * 2 + 1];
                float r = (o & 1) ? (q * cs + qp * sn) : (q * cs - qp * sn);
                Qr[((size_t)((b * NH + h) * SEQ + i)) * 2048 + rr * 64 + dd] = (bfx)(r * zs);
            }
}

// ---------------- kv GEMM: xb[32768,256] @ wkvT^T ---------------------------
// 1-D grid 2048, XCD swizzle. xt<4: K half -> rotary -> Kr; xt>=4: V half ->
// LDS transpose -> coalesced Vt[bh][rd][i] stores.
__global__ void kvgemm_kernel(const bfx* __restrict__ A, const bfx* __restrict__ B,
                              const float* __restrict__ tab,
                              bfx* __restrict__ Kr, bfx* __restrict__ Vt) {
    GEMM_PROLOGUE
    int g = blockIdx.x;
    int y = ((g >> 6) << 3) | (g & 7);     // 0..255
    int xt = (g >> 3) & 7;                 // 0..7
    int m0 = y * 128, n0 = xt * 128;
    gemm_tile(A, CDIM, B, CDIM, m0, n0, CDIM, As, Bs, acc);
    int bn = m0 >> 9, b = bn >> 5, rr = bn & 31;
    if (xt < 4) {
        // ---- K half: rotary epilogue, direct 32B-segment stores ----
        #pragma unroll
        for (int mi = 0; mi < 4; ++mi)
            #pragma unroll
            for (int ni = 0; ni < 4; ++ni)
                #pragma unroll
                for (int rg = 0; rg < 4; ++rg) {
                    int m = m0 + wm + mi * 16 + quad * 4 + rg;
                    int i = m & (SEQ - 1);
                    int o = n0 + wn + ni * 16 + col;
                    float v  = acc[mi][ni][rg];
                    float vp = __shfl_xor(v, 1);
                    int h = o >> 6, dd = o & 63, j = dd >> 1;
                    float sn = tab[(i * 32 + j) * 2], cs = tab[(i * 32 + j) * 2 + 1];
                    float r = (o & 1) ? (v * cs + vp * sn) : (v * cs - vp * sn);
                    Kr[((size_t)((b * NH + h) * SEQ + i)) * 2048 + rr * 64 + dd] = (bfx)r;
                }
    } else {
        // ---- V half: two 64-col LDS transpose passes -> coalesced Vt ----
        int no0 = n0 - INNERD;          // 0,128,256,384
        int h0  = no0 >> 6;             // head base (0,2,4,6)
        int i0  = m0 & (SEQ - 1);
        bfx* Ts = smem;                 // 64 x TST bf16 = 17408 B <= 20480 B
        #pragma unroll
        for (int p = 0; p < 2; ++p) {
            __syncthreads();
            if ((wave & 1) == p) {      // waves with wn == p*64 own these cols
                #pragma unroll
                for (int mi = 0; mi < 4; ++mi)
                    #pragma unroll
                    for (int ni = 0; ni < 4; ++ni) {
                        int nl = ni * 16 + col;          // 0..63
                        int ml = wm + mi * 16 + quad * 4;
                        bf16x4 pk;
                        #pragma unroll
                        for (int rg = 0; rg < 4; ++rg) pk[rg] = (bfx)acc[mi][ni][rg];
                        *(bf16x4*)&Ts[nl * TST + ml] = pk;
                    }
            }
            __syncthreads();
            #pragma unroll
            for (int e = 0; e < 4; ++e) {
                int row = (tid >> 4) + e * 16;           // 0..63 = dd
                int chunk = tid & 15;
                bf16x8 v = *(const bf16x8*)&Ts[row * TST + chunk * 8];
                size_t rv = (size_t)(b * NH + h0 + p) * 2048 + rr * 64 + row;
                *(bf16x8*)&Vt[rv * SEQ + i0 + chunk * 8] = v;
            }
        }
    }
}

// ---------------- dots split-K=2: S_part[ks] = Qr[:,ksK:] @ Kr[:,ksK:]^T ---
// 1-D grid 512, XCD swizzle: all 32 blocks (16 tiles x 2 ks) of one bh share
// id%8 (one XCD). 2 blocks/CU -> inter-block overlap hides barrier drains.
__global__ void dots_kernel(const bfx* __restrict__ Qr, const bfx* __restrict__ Kr,
                            float* __restrict__ Sp0, float* __restrict__ Sp1) {
    GEMM_PROLOGUE
    int g = blockIdx.x;                    // 0..511
    int bh   = (g & 7) | (((g >> 8) & 1) << 3);
    int work = (g >> 3) & 31;              // 0..31
    int tile = work & 15;
    int ks   = work >> 4;                  // K-half 0/1
    int m0 = (tile >> 2) * 128, n0 = (tile & 3) * 128;
    const bfx* A = Qr + (size_t)bh * SEQ * 2048 + ks * 1024;
    const bfx* B = Kr + (size_t)bh * SEQ * 2048 + ks * 1024;
    gemm_tile(A, 2048, B, 2048, m0, n0, 1024, As, Bs, acc);
    float* S = (ks ? Sp1 : Sp0) + (size_t)bh * SEQ * SEQ;
    #pragma unroll
    for (int mi = 0; mi < 4; ++mi)
        #pragma unroll
        for (int ni = 0; ni < 4; ++ni)
            #pragma unroll
            for (int rg = 0; rg < 4; ++rg) {
                int i = m0 + wm + mi * 16 + quad * 4 + rg;
                int j = n0 + wn + ni * 16 + col;
                S[(size_t)i * SEQ + j] = acc[mi][ni][rg];
            }
}

// ---------------- softmax: (Sp0+Sp1) f32 -> Pb bf16 ------------------------
__global__ void softmax_kernel(const int* __restrict__ m_any,
                               const float* __restrict__ Sp0,
                               const float* __restrict__ Sp1,
                               bfx* __restrict__ Pb) {
    int i = blockIdx.x, bh = blockIdx.y;
    int b = bh >> 3;
    size_t roff = ((size_t)bh * SEQ + i) * SEQ;
    const float* r0 = Sp0 + roff;
    const float* r1 = Sp1 + roff;
    bfx* prow = Pb + roff;
    const int* ma = m_any + b * SEQ;
    int fi = ma[i];
    int t = threadIdx.x;
    float v0 = (fi && ma[t])       ? r0[t]       + r1[t]       : -FLT_MAX;
    float v1 = (fi && ma[t + 256]) ? r0[t + 256] + r1[t + 256] : -FLT_MAX;
    __shared__ float red[256];
    red[t] = fmaxf(v0, v1);
    __syncthreads();
    for (int s = 128; s > 0; s >>= 1) {
        if (t < s) red[t] = fmaxf(red[t], red[t + s]);
        __syncthreads();
    }
    float mx = red[0];
    __syncthreads();
    float e0 = __expf(v0 - mx);
    float e1 = __expf(v1 - mx);
    red[t] = e0 + e1;
    __syncthreads();
    for (int s = 128; s > 0; s >>= 1) {
        if (t < s) red[t] += red[t + s];
        __syncthreads();
    }
    float inv = 1.0f / red[0];
    prow[t]       = (bfx)(e0 * inv);
    prow[t + 256] = (bfx)(e1 * inv);
}

// ---------------- PV: per bh: O[i,rd] = Pb[512,512] @ Vt[2048,512]^T -------
// 1-D grid 1024, XCD swizzle: all 64 tiles of one bh share id%8 (one XCD)
__global__ void pv_kernel(const bfx* __restrict__ Pb, const bfx* __restrict__ Vt,
                          bfx* __restrict__ Obuf) {
    GEMM_PROLOGUE
    int g = blockIdx.x;                    // 0..1023
    int bh   = (g & 7) | (((g >> 9) & 1) << 3);
    int tile = (g >> 3) & 63;
    int m0 = (tile >> 4) * 128, n0 = (tile & 15) * 128;  // 4 i-tiles x 16 rd-tiles
    int b = bh >> 3, h = bh & 7;
    const bfx* A = Pb + (size_t)bh * SEQ * SEQ;
    const bfx* B = Vt + (size_t)bh * 2048 * SEQ;
    gemm_tile(A, SEQ, B, SEQ, m0, n0, SEQ, As, Bs, acc);
    #pragma unroll
    for (int mi = 0; mi < 4; ++mi)
        #pragma unroll
        for (int ni = 0; ni < 4; ++ni)
            #pragma unroll
            for (int rg = 0; rg < 4; ++rg) {
                int i = m0 + wm + mi * 16 + quad * 4 + rg;
                int rd = n0 + wn + ni * 16 + col;
                int rr = rd >> 6, dd = rd & 63;
                Obuf[((size_t)((b * RT + rr) * SEQ + i)) * INNERD + h * DH + dd] =
                    (bfx)acc[mi][ni][rg];
            }
}

// ---------------- out: Obuf[32768,512] @ woT^T + b_o -> f32 ----------------
// 1-D grid 512, XCD swizzle
__global__ void out_kernel(const bfx* __restrict__ A, const bfx* __restrict__ B,
                           const float* __restrict__ b_o, float* __restrict__ out) {
    GEMM_PROLOGUE
    int g = blockIdx.x;
    int y = ((g >> 4) << 3) | (g & 7);     // 0..255
    int xt = (g >> 3) & 1;
    int m0 = y * 128, n0 = xt * 128;
    gemm_tile(A, INNERD, B, INNERD, m0, n0, INNERD, As, Bs, acc);
    #pragma unroll
    for (int mi = 0; mi < 4; ++mi)
        #pragma unroll
        for (int ni = 0; ni < 4; ++ni)
            #pragma unroll
            for (int rg = 0; rg < 4; ++rg) {
                int m = m0 + wm + mi * 16 + quad * 4 + rg;
                int c = n0 + wn + ni * 16 + col;
                out[(size_t)m * CDIM + c] = acc[mi][ni][rg] + b_o[c];
            }
}

// ---------------- workspace layout (bytes) ---------------------------------
// 0         tab f32                                 131072
// 131072    m_any int32[1024]                         4096
// 135168    has_rows int32[64]                         256
// 135424    inv_nr f32 (+pad)                          256
// 135680    xb16 bf16 [8388608 elems]  16777216  (REUSED: Sp0 f32 after kvgemm)
// 16912896  hdw  bf16 [8388608 elems]  16777216  (REUSED: Sp1 f32 after qgemm)
// 33690112  pw16 bf16                    262144
// 33952256  wkvT bf16                    524288
// 34476544  woT  bf16                    262144
// 34738688  Qr   bf16 [16777216 elems] 33554432  (REUSED: Obuf bf16 [16777216
//           elems = 33554432 BYTES] after dots — full region!)
// 68293120  Kr   bf16 [16777216 elems] 33554432
// 101847552 Vt   bf16 [16777216 elems] 33554432
// 135401984 Pb   bf16 [4194304 elems]   8388608   (fresh space; R2 proved
//                                                  ws >= 151130624)
// end 143790592

extern "C" void kernel_launch(void* const* d_in, const int* in_sizes, int n_in,
                              void* d_out, int out_size, void* d_ws, size_t ws_size,
                              hipStream_t stream) {
    const float* x    = (const float*)d_in[0];
    const int*   mask = (const int*)d_in[1];
    const float* dw_w = (const float*)d_in[3];
    const float* dw_b = (const float*)d_in[4];
    const float* pw_w = (const float*)d_in[5];
    const float* pw_b = (const float*)d_in[6];
    const float* w_kv = (const float*)d_in[7];
    const float* w_o  = (const float*)d_in[8];
    const float* b_o  = (const float*)d_in[9];
    float* out = (float*)d_out;

    char* ws = (char*)d_ws;
    float* tab   = (float*)(ws + 0);
    int*   m_any = (int*)(ws + 131072);
    int*   hrows = (int*)(ws + 135168);
    float* invnr = (float*)(ws + 135424);
    bfx*   xb16  = (bfx*)(ws + 135680);
    float* Sp0   = (float*)(ws + 135680);      // alias xb16 (dead after kvgemm)
    bfx*   hdw   = (bfx*)(ws + 16912896);
    float* Sp1   = (float*)(ws + 16912896);    // alias hdw (dead after qgemm)
    bfx*   pw16  = (bfx*)(ws + 33690112);
    bfx*   wkvT  = (bfx*)(ws + 33952256);
    bfx*   woT   = (bfx*)(ws + 34476544);
    bfx*   Qr    = (bfx*)(ws + 34738688);
    bfx*   Obuf  = (bfx*)(ws + 34738688);      // alias Qr FULL region (dead after dots)
    bfx*   Kr    = (bfx*)(ws + 68293120);
    bfx*   Vt    = (bfx*)(ws + 101847552);
    bfx*   Pb    = (bfx*)(ws + 135401984);     // fresh space, disjoint from Obuf

    if (ws_size < 143790592u) return;

    hipLaunchKernelGGL(prep_kernel,  dim3(9922),    dim3(256), 0, stream,
                       x, pw_w, w_kv, w_o, mask, xb16, pw16, wkvT, woT,
                       tab, m_any, hrows, invnr);
    hipLaunchKernelGGL(conv_kernel,  dim3(64, 8),   dim3(256), 0, stream, xb16, dw_w, dw_b, hdw);
    hipLaunchKernelGGL(qgemm_kernel, dim3(1024),    dim3(256), 0, stream, hdw, pw16, pw_b, hrows, invnr, tab, Qr);
    hipLaunchKernelGGL(kvgemm_kernel,dim3(2048),    dim3(256), 0, stream, xb16, wkvT, tab, Kr, Vt);
    hipLaunchKernelGGL(dots_kernel,  dim3(512),     dim3(256), 0, stream, Qr, Kr, Sp0, Sp1);
    hipLaunchKernelGGL(softmax_kernel, dim3(SEQ, 16), dim3(256), 0, stream, m_any, Sp0, Sp1, Pb);
    hipLaunchKernelGGL(pv_kernel,    dim3(1024),    dim3(256), 0, stream, Pb, Vt, Obuf);
    hipLaunchKernelGGL(out_kernel,   dim3(512),     dim3(256), 0, stream, Obuf, woT, b_o, out);
}

// Round 10
// 268.017 us; speedup vs baseline: 1.2799x; 1.0162x over previous
//
#include <hip/hip_runtime.h>
#include <hip/hip_bf16.h>
#include <float.h>
#include <math.h>

typedef __bf16 bfx;
typedef __attribute__((ext_vector_type(8))) __bf16 bf16x8;
typedef __attribute__((ext_vector_type(4))) __bf16 bf16x4;
typedef __attribute__((ext_vector_type(2))) __bf16 bf16x2;
typedef __attribute__((ext_vector_type(4))) float f32x4;

#define SEQ    512
#define CDIM   256
#define NH     8
#define DH     64
#define INNERD 512
#define RT     32
#define NB     2
#define KW     15
#define PW     7
#define LDT    40   // padded LDS row stride (bf16): 80B rows -> <=2-way conflicts
#define TST    136  // V-transpose stage stride (bf16): 272B, 16B-aligned

// ================= fused prep ==============================================
// grid = 8192 (x) + 64 (sincos) + 128 (pw) + 64 (wkvT tiles) + 32 (woT tiles)
//        + 2 (mask) = 8482
__global__ void prep_kernel(const float* __restrict__ x,
                            const float* __restrict__ pw_w,
                            const float* __restrict__ w_kv,
                            const float* __restrict__ w_o,
                            const int*   __restrict__ mask,
                            bfx* __restrict__ xb16, bfx* __restrict__ pw16,
                            bfx* __restrict__ wkvT, bfx* __restrict__ woT,
                            float* __restrict__ tab,
                            int* __restrict__ m_any, int* __restrict__ has_rows,
                            float* __restrict__ inv_nr) {
    __shared__ float tileS[64][65];
    int bid = blockIdx.x, tid = threadIdx.x;
    if (bid < 8192) {                       // x -> bf16, 4 elems/thread
        int idx = bid * 256 + tid;
        float4 v = ((const float4*)x)[idx];
        bfx* d = xb16 + idx * 4;
        d[0] = (bfx)v.x; d[1] = (bfx)v.y; d[2] = (bfx)v.z; d[3] = (bfx)v.w;
        return;
    }
    int b2 = bid - 8192;
    if (b2 < 64) {                          // sincos table
        int idx = b2 * 256 + tid;
        int i = idx >> 5, j = idx & 31;
        float inv_freq = powf(10000.0f, -(float)j / 32.0f);
        float s, c;
        sincosf((float)i * inv_freq, &s, &c);
        tab[idx * 2] = s; tab[idx * 2 + 1] = c;
        return;
    }
    b2 -= 64;
    if (b2 < 128) {                         // pw_w -> bf16 (already [n][k])
        int idx = b2 * 256 + tid;
        float4 v = ((const float4*)pw_w)[idx];
        bfx* d = pw16 + idx * 4;
        d[0] = (bfx)v.x; d[1] = (bfx)v.y; d[2] = (bfx)v.z; d[3] = (bfx)v.w;
        return;
    }
    b2 -= 128;
    if (b2 < 64) {                          // w_kv[256,1024] -> wkvT[n*256+k], 64x64 tiles
        int kt = b2 & 3, nt = b2 >> 2;
        int k0 = kt * 64, n0 = nt * 64;
        #pragma unroll
        for (int e = 0; e < 16; ++e) {
            int idx = e * 256 + tid;
            int rr = idx >> 6, cc = idx & 63;
            tileS[rr][cc] = w_kv[(size_t)(k0 + rr) * 1024 + n0 + cc];
        }
        __syncthreads();
        #pragma unroll
        for (int e = 0; e < 16; ++e) {
            int idx = e * 256 + tid;
            int rr = idx >> 6, cc = idx & 63;
            wkvT[(size_t)(n0 + rr) * 256 + k0 + cc] = (bfx)tileS[cc][rr];
        }
        return;
    }
    b2 -= 64;
    if (b2 < 32) {                          // w_o[512,256] -> woT[n*512+k], 64x64 tiles
        int kt = b2 & 7, nt = b2 >> 3;
        int k0 = kt * 64, n0 = nt * 64;
        #pragma unroll
        for (int e = 0; e < 16; ++e) {
            int idx = e * 256 + tid;
            int rr = idx >> 6, cc = idx & 63;
            tileS[rr][cc] = w_o[(size_t)(k0 + rr) * CDIM + n0 + cc];
        }
        __syncthreads();
        #pragma unroll
        for (int e = 0; e < 16; ++e) {
            int idx = e * 256 + tid;
            int rr = idx >> 6, cc = idx & 63;
            woT[(size_t)(n0 + rr) * 512 + k0 + cc] = (bfx)tileS[cc][rr];
        }
        return;
    }
    b2 -= 32;
    {                                       // mask stats, b = b2 (0..1)
        int b = b2;
        #pragma unroll
        for (int half = 0; half < 2; ++half) {
            int i = tid + half * 256;
            int any_col = 0;
            for (int rr = 0; rr < RT; ++rr)
                any_col |= mask[(size_t)(b * RT + rr) * SEQ + i];
            m_any[b * SEQ + i] = any_col ? 1 : 0;
        }
        __shared__ int hr[RT];
        if (tid < RT) {
            int a = 0;
            const int* mrow = mask + (size_t)(b * RT + tid) * SEQ;
            for (int j = 0; j < SEQ; ++j) a |= mrow[j];
            hr[tid] = a ? 1 : 0;
            has_rows[b * RT + tid] = hr[tid];
        }
        __syncthreads();
        if (tid == 0) {
            int s = 0;
            for (int rr = 0; rr < RT; ++rr) s += hr[rr];
            inv_nr[b] = (s > 0) ? rsqrtf((float)s) : 0.0f;
        }
    }
}

// ---------------- depthwise conv1d: 2 ch/thread, 32-row chunks -------------
__global__ void conv_kernel(const bfx* __restrict__ xb,
                            const float* __restrict__ dw_w,
                            const float* __restrict__ dw_b,
                            bfx* __restrict__ hdw) {
    int bn  = blockIdx.x;
    int grp = threadIdx.x >> 7;
    int t   = threadIdx.x & 127;
    int i0  = blockIdx.y * 64 + grp * 32;
    int c   = t * 2;
    const bf16x2* xc = (const bf16x2*)(xb + (size_t)bn * SEQ * CDIM) + t;
    float w0[KW], w1[KW];
    #pragma unroll
    for (int k = 0; k < KW; ++k) { w0[k] = dw_w[c * KW + k]; w1[k] = dw_w[(c + 1) * KW + k]; }
    float b0 = dw_b[c], b1 = dw_b[c + 1];
    float win0[KW], win1[KW];
    #pragma unroll
    for (int k = 0; k < KW; ++k) {
        int p = i0 - PW + k;
        if (p >= 0 && p < SEQ) {
            bf16x2 v = xc[(size_t)p * 128];
            win0[k] = (float)v[0]; win1[k] = (float)v[1];
        } else { win0[k] = 0.0f; win1[k] = 0.0f; }
    }
    bf16x2* orow = (bf16x2*)(hdw + ((size_t)bn * SEQ + i0) * CDIM) + t;
    for (int i = i0; i < i0 + 32; ++i) {
        float a0 = b0, a1 = b1;
        #pragma unroll
        for (int k = 0; k < KW; ++k) { a0 += win0[k] * w0[k]; a1 += win1[k] * w1[k]; }
        bf16x2 o; o[0] = (bfx)a0; o[1] = (bfx)a1;
        *orow = o;
        orow += 128;
        #pragma unroll
        for (int k = 0; k < KW - 1; ++k) { win0[k] = win0[k + 1]; win1[k] = win1[k + 1]; }
        int p = i + PW + 1;
        if (p < SEQ) {
            bf16x2 v = xc[(size_t)p * 128];
            win0[KW - 1] = (float)v[0]; win1[KW - 1] = (float)v[1];
        } else { win0[KW - 1] = 0.0f; win1[KW - 1] = 0.0f; }
    }
}

// ---------------- shared 128x128 MFMA tile ---------------------------------
__device__ __forceinline__ void gemm_tile(const bfx* __restrict__ A, int lda,
                                          const bfx* __restrict__ B, int ldb,
                                          int m0, int n0, int K,
                                          bfx* As, bfx* Bs, f32x4 acc[4][4]) {
    int tid = threadIdx.x;
    int wave = tid >> 6, lane = tid & 63;
    int wm = (wave >> 1) * 64, wn = (wave & 1) * 64;
    int col = lane & 15, quad = lane >> 4;
    for (int k0 = 0; k0 < K; k0 += 32) {
        #pragma unroll
        for (int r = 0; r < 2; ++r) {
            int v = tid + r * 256;
            int row = v >> 2, kv = (v & 3) * 8;
            *(bf16x8*)&As[row * LDT + kv] = *(const bf16x8*)&A[(size_t)(m0 + row) * lda + k0 + kv];
            *(bf16x8*)&Bs[row * LDT + kv] = *(const bf16x8*)&B[(size_t)(n0 + row) * ldb + k0 + kv];
        }
        __syncthreads();
        bf16x8 af[4], bff[4];
        #pragma unroll
        for (int f = 0; f < 4; ++f) {
            af[f]  = *(const bf16x8*)&As[(wm + f * 16 + col) * LDT + quad * 8];
            bff[f] = *(const bf16x8*)&Bs[(wn + f * 16 + col) * LDT + quad * 8];
        }
        #pragma unroll
        for (int mi = 0; mi < 4; ++mi)
            #pragma unroll
            for (int ni = 0; ni < 4; ++ni)
                acc[mi][ni] = __builtin_amdgcn_mfma_f32_16x16x32_bf16(af[mi], bff[ni], acc[mi][ni], 0, 0, 0);
        __syncthreads();
    }
}

#define GEMM_PROLOGUE \
    __shared__ __align__(16) bfx smem[2 * 128 * LDT]; \
    bfx* As = smem; bfx* Bs = smem + 128 * LDT; \
    f32x4 acc[4][4]; \
    _Pragma("unroll") for (int i_ = 0; i_ < 4; ++i_) \
    _Pragma("unroll") for (int j_ = 0; j_ < 4; ++j_) acc[i_][j_] = (f32x4){0.f, 0.f, 0.f, 0.f}; \
    int tid = threadIdx.x; \
    int wave = tid >> 6, lane = tid & 63; \
    int wm = (wave >> 1) * 64, wn = (wave & 1) * 64; \
    int col = lane & 15, quad = lane >> 4;

// ---------------- merged QKV GEMM: grid 3072 -------------------------------
// g<1024: q role (hdw @ pw16^T -> rotary*scale -> Qr)
// g>=1024: kv role (xb16 @ wkvT^T -> Kr rotary / Vt transposed)
// XCD swizzle preserved in both halves (all sharers of an A-stripe have same g%8)
__global__ void qkv_kernel(const bfx* __restrict__ Aq, const bfx* __restrict__ Bq,
                           const bfx* __restrict__ Akv, const bfx* __restrict__ Bkv,
                           const float* __restrict__ pw_b,
                           const int* __restrict__ has_rows,
                           const float* __restrict__ inv_nr,
                           const float* __restrict__ tab,
                           bfx* __restrict__ Qr, bfx* __restrict__ Kr,
                           bfx* __restrict__ Vt) {
    GEMM_PROLOGUE
    int g = blockIdx.x;
    if (g < 1024) {
        // ===================== q role =====================
        int y = ((g >> 5) << 3) | (g & 7);     // 0..255
        int xt = (g >> 3) & 3;                 // 0..3
        int m0 = y * 128, n0 = xt * 128;
        gemm_tile(Aq, CDIM, Bq, CDIM, m0, n0, CDIM, As, Bs, acc);
        int bn = m0 >> 9, b = bn >> 5, rr = bn & 31;
        float zs = has_rows[bn] ? 0.125f * inv_nr[b] : 0.0f;
        #pragma unroll
        for (int mi = 0; mi < 4; ++mi)
            #pragma unroll
            for (int ni = 0; ni < 4; ++ni)
                #pragma unroll
                for (int rg = 0; rg < 4; ++rg) {
                    int m = m0 + wm + mi * 16 + quad * 4 + rg;
                    int i = m & (SEQ - 1);
                    int o = n0 + wn + ni * 16 + col;
                    float v  = acc[mi][ni][rg];
                    float vp = __shfl_xor(v, 1);
                    float q  = v + pw_b[o];
                    float qp = vp + pw_b[o ^ 1];
                    int h = o >> 6, dd = o & 63, j = dd >> 1;
                    float sn = tab[(i * 32 + j) * 2], cs = tab[(i * 32 + j) * 2 + 1];
                    float r = (o & 1) ? (q * cs + qp * sn) : (q * cs - qp * sn);
                    Qr[((size_t)((b * NH + h) * SEQ + i)) * 2048 + rr * 64 + dd] = (bfx)(r * zs);
                }
    } else {
        // ===================== kv role =====================
        g -= 1024;
        int y = ((g >> 6) << 3) | (g & 7);     // 0..255
        int xt = (g >> 3) & 7;                 // 0..7
        int m0 = y * 128, n0 = xt * 128;
        gemm_tile(Akv, CDIM, Bkv, CDIM, m0, n0, CDIM, As, Bs, acc);
        int bn = m0 >> 9, b = bn >> 5, rr = bn & 31;
        if (xt < 4) {
            // K half: rotary epilogue, direct 32B-segment stores
            #pragma unroll
            for (int mi = 0; mi < 4; ++mi)
                #pragma unroll
                for (int ni = 0; ni < 4; ++ni)
                    #pragma unroll
                    for (int rg = 0; rg < 4; ++rg) {
                        int m = m0 + wm + mi * 16 + quad * 4 + rg;
                        int i = m & (SEQ - 1);
                        int o = n0 + wn + ni * 16 + col;
                        float v  = acc[mi][ni][rg];
                        float vp = __shfl_xor(v, 1);
                        int h = o >> 6, dd = o & 63, j = dd >> 1;
                        float sn = tab[(i * 32 + j) * 2], cs = tab[(i * 32 + j) * 2 + 1];
                        float r = (o & 1) ? (v * cs + vp * sn) : (v * cs - vp * sn);
                        Kr[((size_t)((b * NH + h) * SEQ + i)) * 2048 + rr * 64 + dd] = (bfx)r;
                    }
        } else {
            // V half: two 64-col LDS transpose passes -> coalesced Vt
            int no0 = n0 - INNERD;          // 0,128,256,384
            int h0  = no0 >> 6;             // head base (0,2,4,6)
            int i0  = m0 & (SEQ - 1);
            bfx* Ts = smem;                 // 64 x TST bf16 = 17408 B <= 20480 B
            #pragma unroll
            for (int p = 0; p < 2; ++p) {
                __syncthreads();
                if ((wave & 1) == p) {      // waves with wn == p*64 own these cols
                    #pragma unroll
                    for (int mi = 0; mi < 4; ++mi)
                        #pragma unroll
                        for (int ni = 0; ni < 4; ++ni) {
                            int nl = ni * 16 + col;          // 0..63
                            int ml = wm + mi * 16 + quad * 4;
                            bf16x4 pk;
                            #pragma unroll
                            for (int rg = 0; rg < 4; ++rg) pk[rg] = (bfx)acc[mi][ni][rg];
                            *(bf16x4*)&Ts[nl * TST + ml] = pk;
                        }
                }
                __syncthreads();
                #pragma unroll
                for (int e = 0; e < 4; ++e) {
                    int row = (tid >> 4) + e * 16;           // 0..63 = dd
                    int chunk = tid & 15;
                    bf16x8 v = *(const bf16x8*)&Ts[row * TST + chunk * 8];
                    size_t rv = (size_t)(b * NH + h0 + p) * 2048 + rr * 64 + row;
                    *(bf16x8*)&Vt[rv * SEQ + i0 + chunk * 8] = v;
                }
            }
        }
    }
}

// ---------------- dots split-K=2: S_part[ks] = Qr[:,ksK:] @ Kr[:,ksK:]^T ---
// 1-D grid 512, XCD swizzle: all 32 blocks of one bh share id%8 (one XCD)
__global__ void dots_kernel(const bfx* __restrict__ Qr, const bfx* __restrict__ Kr,
                            float* __restrict__ Sp0, float* __restrict__ Sp1) {
    GEMM_PROLOGUE
    int g = blockIdx.x;                    // 0..511
    int bh   = (g & 7) | (((g >> 8) & 1) << 3);
    int work = (g >> 3) & 31;              // 0..31
    int tile = work & 15;
    int ks   = work >> 4;                  // K-half 0/1
    int m0 = (tile >> 2) * 128, n0 = (tile & 3) * 128;
    const bfx* A = Qr + (size_t)bh * SEQ * 2048 + ks * 1024;
    const bfx* B = Kr + (size_t)bh * SEQ * 2048 + ks * 1024;
    gemm_tile(A, 2048, B, 2048, m0, n0, 1024, As, Bs, acc);
    float* S = (ks ? Sp1 : Sp0) + (size_t)bh * SEQ * SEQ;
    #pragma unroll
    for (int mi = 0; mi < 4; ++mi)
        #pragma unroll
        for (int ni = 0; ni < 4; ++ni)
            #pragma unroll
            for (int rg = 0; rg < 4; ++rg) {
                int i = m0 + wm + mi * 16 + quad * 4 + rg;
                int j = n0 + wn + ni * 16 + col;
                S[(size_t)i * SEQ + j] = acc[mi][ni][rg];
            }
}

// ---------------- softmax: (Sp0+Sp1) f32 -> Pb bf16 ------------------------
__global__ void softmax_kernel(const int* __restrict__ m_any,
                               const float* __restrict__ Sp0,
                               const float* __restrict__ Sp1,
                               bfx* __restrict__ Pb) {
    int i = blockIdx.x, bh = blockIdx.y;
    int b = bh >> 3;
    size_t roff = ((size_t)bh * SEQ + i) * SEQ;
    const float* r0 = Sp0 + roff;
    const float* r1 = Sp1 + roff;
    bfx* prow = Pb + roff;
    const int* ma = m_any + b * SEQ;
    int fi = ma[i];
    int t = threadIdx.x;
    float v0 = (fi && ma[t])       ? r0[t]       + r1[t]       : -FLT_MAX;
    float v1 = (fi && ma[t + 256]) ? r0[t + 256] + r1[t + 256] : -FLT_MAX;
    __shared__ float red[256];
    red[t] = fmaxf(v0, v1);
    __syncthreads();
    for (int s = 128; s > 0; s >>= 1) {
        if (t < s) red[t] = fmaxf(red[t], red[t + s]);
        __syncthreads();
    }
    float mx = red[0];
    __syncthreads();
    float e0 = __expf(v0 - mx);
    float e1 = __expf(v1 - mx);
    red[t] = e0 + e1;
    __syncthreads();
    for (int s = 128; s > 0; s >>= 1) {
        if (t < s) red[t] += red[t + s];
        __syncthreads();
    }
    float inv = 1.0f / red[0];
    prow[t]       = (bfx)(e0 * inv);
    prow[t + 256] = (bfx)(e1 * inv);
}

// ---------------- PV: per bh: O[i,rd] = Pb[512,512] @ Vt[2048,512]^T -------
// 1-D grid 1024, XCD swizzle: all 64 tiles of one bh share id%8 (one XCD)
__global__ void pv_kernel(const bfx* __restrict__ Pb, const bfx* __restrict__ Vt,
                          bfx* __restrict__ Obuf) {
    GEMM_PROLOGUE
    int g = blockIdx.x;                    // 0..1023
    int bh   = (g & 7) | (((g >> 9) & 1) << 3);
    int tile = (g >> 3) & 63;
    int m0 = (tile >> 4) * 128, n0 = (tile & 15) * 128;  // 4 i-tiles x 16 rd-tiles
    int b = bh >> 3, h = bh & 7;
    const bfx* A = Pb + (size_t)bh * SEQ * SEQ;
    const bfx* B = Vt + (size_t)bh * 2048 * SEQ;
    gemm_tile(A, SEQ, B, SEQ, m0, n0, SEQ, As, Bs, acc);
    #pragma unroll
    for (int mi = 0; mi < 4; ++mi)
        #pragma unroll
        for (int ni = 0; ni < 4; ++ni)
            #pragma unroll
            for (int rg = 0; rg < 4; ++rg) {
                int i = m0 + wm + mi * 16 + quad * 4 + rg;
                int rd = n0 + wn + ni * 16 + col;
                int rr = rd >> 6, dd = rd & 63;
                Obuf[((size_t)((b * RT + rr) * SEQ + i)) * INNERD + h * DH + dd] =
                    (bfx)acc[mi][ni][rg];
            }
}

// ---------------- out: Obuf[32768,512] @ woT^T + b_o -> f32 ----------------
// 1-D grid 512, XCD swizzle
__global__ void out_kernel(const bfx* __restrict__ A, const bfx* __restrict__ B,
                           const float* __restrict__ b_o, float* __restrict__ out) {
    GEMM_PROLOGUE
    int g = blockIdx.x;
    int y = ((g >> 4) << 3) | (g & 7);     // 0..255
    int xt = (g >> 3) & 1;
    int m0 = y * 128, n0 = xt * 128;
    gemm_tile(A, INNERD, B, INNERD, m0, n0, INNERD, As, Bs, acc);
    #pragma unroll
    for (int mi = 0; mi < 4; ++mi)
        #pragma unroll
        for (int ni = 0; ni < 4; ++ni)
            #pragma unroll
            for (int rg = 0; rg < 4; ++rg) {
                int m = m0 + wm + mi * 16 + quad * 4 + rg;
                int c = n0 + wn + ni * 16 + col;
                out[(size_t)m * CDIM + c] = acc[mi][ni][rg] + b_o[c];
            }
}

// ---------------- workspace layout (bytes) ---------------------------------
// 0         tab f32                                 131072
// 131072    m_any int32[1024]                         4096
// 135168    has_rows int32[64]                         256
// 135424    inv_nr f32 (+pad)                          256
// 135680    xb16 bf16 [8388608 elems]  16777216  (REUSED: Sp0 f32 after qkv)
// 16912896  hdw  bf16 [8388608 elems]  16777216  (REUSED: Sp1 f32 after qkv)
// 33690112  pw16 bf16                    262144
// 33952256  wkvT bf16                    524288
// 34476544  woT  bf16                    262144
// 34738688  Qr   bf16 [16777216 elems] 33554432  (REUSED: Obuf, full region, after dots)
// 68293120  Kr   bf16 [16777216 elems] 33554432
// 101847552 Vt   bf16 [16777216 elems] 33554432
// 135401984 Pb   bf16 [4194304 elems]   8388608
// end 143790592

extern "C" void kernel_launch(void* const* d_in, const int* in_sizes, int n_in,
                              void* d_out, int out_size, void* d_ws, size_t ws_size,
                              hipStream_t stream) {
    const float* x    = (const float*)d_in[0];
    const int*   mask = (const int*)d_in[1];
    const float* dw_w = (const float*)d_in[3];
    const float* dw_b = (const float*)d_in[4];
    const float* pw_w = (const float*)d_in[5];
    const float* pw_b = (const float*)d_in[6];
    const float* w_kv = (const float*)d_in[7];
    const float* w_o  = (const float*)d_in[8];
    const float* b_o  = (const float*)d_in[9];
    float* out = (float*)d_out;

    char* ws = (char*)d_ws;
    float* tab   = (float*)(ws + 0);
    int*   m_any = (int*)(ws + 131072);
    int*   hrows = (int*)(ws + 135168);
    float* invnr = (float*)(ws + 135424);
    bfx*   xb16  = (bfx*)(ws + 135680);
    float* Sp0   = (float*)(ws + 135680);      // alias xb16 (dead after qkv)
    bfx*   hdw   = (bfx*)(ws + 16912896);
    float* Sp1   = (float*)(ws + 16912896);    // alias hdw (dead after qkv)
    bfx*   pw16  = (bfx*)(ws + 33690112);
    bfx*   wkvT  = (bfx*)(ws + 33952256);
    bfx*   woT   = (bfx*)(ws + 34476544);
    bfx*   Qr    = (bfx*)(ws + 34738688);
    bfx*   Obuf  = (bfx*)(ws + 34738688);      // alias Qr FULL region (dead after dots)
    bfx*   Kr    = (bfx*)(ws + 68293120);
    bfx*   Vt    = (bfx*)(ws + 101847552);
    bfx*   Pb    = (bfx*)(ws + 135401984);     // fresh space, disjoint from Obuf

    if (ws_size < 143790592u) return;

    hipLaunchKernelGGL(prep_kernel,  dim3(8482),    dim3(256), 0, stream,
                       x, pw_w, w_kv, w_o, mask, xb16, pw16, wkvT, woT,
                       tab, m_any, hrows, invnr);
    hipLaunchKernelGGL(conv_kernel,  dim3(64, 8),   dim3(256), 0, stream, xb16, dw_w, dw_b, hdw);
    hipLaunchKernelGGL(qkv_kernel,   dim3(3072),    dim3(256), 0, stream,
                       hdw, pw16, xb16, wkvT, pw_b, hrows, invnr, tab, Qr, Kr, Vt);
    hipLaunchKernelGGL(dots_kernel,  dim3(512),     dim3(256), 0, stream, Qr, Kr, Sp0, Sp1);
    hipLaunchKernelGGL(softmax_kernel, dim3(SEQ, 16), dim3(256), 0, stream, m_any, Sp0, Sp1, Pb);
    hipLaunchKernelGGL(pv_kernel,    dim3(1024),    dim3(256), 0, stream, Pb, Vt, Obuf);
    hipLaunchKernelGGL(out_kernel,   dim3(512),     dim3(256), 0, stream, Obuf, woT, b_o, out);
}